// Round 6
// baseline (794.090 us; speedup 1.0000x reference)
//
#include <hip/hip_runtime.h>
#include <math.h>

#define NNODES 100000
#define NEDGES 1600000
#define NBATCH 64
#define NTILES (NEDGES/64)   // 25000 tiles of 64 edges (4 nodes)

typedef __attribute__((ext_vector_type(8))) short  short8;
typedef __attribute__((ext_vector_type(4))) short  short4v;
typedef __attribute__((ext_vector_type(4))) float  float4v;
typedef unsigned short ushort_t;

__device__ __forceinline__ short f2bf(float f) {           // RTNE fp32->bf16
    unsigned u = __builtin_bit_cast(unsigned, f);
    u += 0x7fffu + ((u >> 16) & 1u);
    return (short)(u >> 16);
}
__device__ __forceinline__ float b2f(short s) {
    unsigned u = ((unsigned)(unsigned short)s) << 16;
    return __builtin_bit_cast(float, u);
}

// max with a row_ror DPP operand: pure-VALU cross-lane (16-lane row rotate).
template<int CTRL>
__device__ __forceinline__ float maxror(float v) {
    int t = __builtin_amdgcn_update_dpp(0, __builtin_bit_cast(int, v),
                                        CTRL, 0xf, 0xf, true);
    return fmaxf(v, __builtin_bit_cast(float, t));
}
__device__ __forceinline__ float red16max(float v) {
    v = maxror<0x128>(v);   // row_ror:8
    v = maxror<0x124>(v);   // row_ror:4
    v = maxror<0x122>(v);   // row_ror:2
    v = maxror<0x121>(v);   // row_ror:1
    return v;               // all 16 lanes of the row now hold the max
}

// Workgroup barrier that releases LDS writes but deliberately leaves global
// (prefetch) loads in flight: __syncthreads() would drain vmcnt(0) and defeat
// the software pipeline (the m97 barrier-drain stall). lgkmcnt(0) before
// s_barrier makes this iteration's ds_writes visible to all waves.
__device__ __forceinline__ void barrier_lds_only() {
    asm volatile("s_waitcnt lgkmcnt(0)" ::: "memory");
    __builtin_amdgcn_sched_barrier(0);
    __builtin_amdgcn_s_barrier();
    __builtin_amdgcn_sched_barrier(0);
}

// Split-bf16-weights MFMA layer, single-bf16 activations, register-prefetched
// gather. A = W^T (M = out-dim), B = x^T (N = edges). D layout (m89):
// col(=edge) = lane&15, row(=out) = (lane>>4)*4 + reg. Weights (hi+lo bf16
// planes) live in registers for the whole block; activations stream through
// LDS as one bf16 plane. The next tile's scattered h[src]/pos[src] rows are
// loaded into registers right after the staging barrier and consumed at the
// next iteration's staging write -> gather latency hides under both GEMMs.
template<int CIN, int H, int O>
__global__ __launch_bounds__(256, 4)
void layer_mfma(const ushort_t* __restrict__ hin, const float* __restrict__ pos,
                const int* __restrict__ srcArr,
                const float* __restrict__ wa, const float* __restrict__ ba,
                const float* __restrict__ wb, const float* __restrict__ bb,
                ushort_t* __restrict__ hout)
{
    constexpr int K1   = CIN + 3;
    constexpr int S1   = ((K1 + 31) / 32) * 32;  // padded K of GEMM1
    constexpr int NS1  = S1 / 32;
    constexpr int MPW1 = H / 64;
    constexpr int NS2  = H / 32;
    constexpr int MPW2 = O / 64;
    constexpr int RSX  = S1 + 8;                 // x row stride (shorts)
    constexpr int RSY  = H + 8;

    __shared__ short smem[64 * RSX + 64 * RSY];
    short* xs = smem;            // [64 edges][x bf16 (S1) | pad]
    short* ys = smem + 64 * RSX; // [64 edges][y bf16 (H)  | pad]

    const int tid  = threadIdx.x;
    const int lane = tid & 63;
    const int w    = tid >> 6;   // wave id 0..3
    const int g    = lane >> 4;  // k-group
    const int c    = lane & 15;
    const int e    = tid & 63;   // edge-in-tile this thread stages
    const int rep  = tid >> 6;   // 16-short slice of the row this thread stages
    const int STRIDE = gridDim.x;

    // Zero all of LDS once: K-pad columns must read as 0.
    {
        short4v z4 = (short4v)0;
        for (int i = tid; i < (64*RSX + 64*RSY)/4; i += 256)
            ((short4v*)smem)[i] = z4;
    }

    // ---- prefetch state + issue: rows/pos for tile `targ` using srcN, then
    // advance srcN to tile targ+STRIDE (clamped). Loads land under compute.
    int srcN = srcArr[blockIdx.x * 64 + e];
    short8 pA, pB;
    float ps0, ps1, ps2, pd0, pd1, pd2;
    auto issue = [&](int targ) {
        const int src = srcN;
        if constexpr (CIN == 3) {
            if (rep == 0) {
                ps0 = pos[src*3+0]; ps1 = pos[src*3+1]; ps2 = pos[src*3+2];
                const int node = targ*4 + (e >> 4);
                pd0 = pos[node*3+0]; pd1 = pos[node*3+1]; pd2 = pos[node*3+2];
            }
        } else {
            const ushort_t* hrow = hin + (size_t)src * CIN + rep*16;
            pA = *(const short8*)(hrow + 0);
            pB = *(const short8*)(hrow + 8);
            if (rep == 0) {
                ps0 = pos[src*3+0]; ps1 = pos[src*3+1]; ps2 = pos[src*3+2];
                const int node = targ*4 + (e >> 4);
                pd0 = pos[node*3+0]; pd1 = pos[node*3+1]; pd2 = pos[node*3+2];
            }
        }
        const int tn = min(targ + STRIDE, NTILES - 1);
        srcN = srcArr[tn*64 + e];
    };
    issue(blockIdx.x);   // tile0's data in flight under the weight build

    // ---- persistent weight fragments (A-operand: row = lane&15) ----
    short8 wah[MPW1][NS1], wal[MPW1][NS1];
    float  bav[MPW1][4];
    #pragma unroll
    for (int mi = 0; mi < MPW1; ++mi) {
        const int mt = mi*4 + w;
        const int h  = mt*16 + c;
        #pragma unroll
        for (int pk = 0; pk < NS1; ++pk) {
            short8 fh, fl;
            #pragma unroll
            for (int j = 0; j < 8; ++j) {
                const int k = pk*32 + g*8 + j;
                float f = (k < K1) ? wa[k*H + h] : 0.f;
                short hi = f2bf(f);
                fh[j] = hi;
                fl[j] = f2bf(f - b2f(hi));
            }
            wah[mi][pk] = fh; wal[mi][pk] = fl;
        }
        #pragma unroll
        for (int r = 0; r < 4; ++r) bav[mi][r] = ba[mt*16 + g*4 + r];
    }
    short8 wbh[MPW2][NS2], wbl[MPW2][NS2];
    float  bbv[MPW2][4];
    #pragma unroll
    for (int mi = 0; mi < MPW2; ++mi) {
        const int mt = mi*4 + w;
        const int o  = mt*16 + c;
        #pragma unroll
        for (int pk = 0; pk < NS2; ++pk) {
            short8 fh, fl;
            #pragma unroll
            for (int j = 0; j < 8; ++j) {
                const int k = pk*32 + g*8 + j;   // k < H always
                float f = wb[k*O + o];
                short hi = f2bf(f);
                fh[j] = hi;
                fl[j] = f2bf(f - b2f(hi));
            }
            wbh[mi][pk] = fh; wbl[mi][pk] = fl;
        }
        #pragma unroll
        for (int r = 0; r < 4; ++r) bbv[mi][r] = bb[mt*16 + g*4 + r];
    }
    __syncthreads();

    for (int tile = blockIdx.x; tile < NTILES; tile += STRIDE) {
        // ---- stage x(tile) from prefetched regs ----
        if constexpr (CIN == 3) {
            if (rep == 0) {
                short8 hv;
                hv[0] = f2bf(ps0); hv[1] = f2bf(ps1); hv[2] = f2bf(ps2);
                hv[3] = f2bf(ps0 - pd0);
                hv[4] = f2bf(ps1 - pd1);
                hv[5] = f2bf(ps2 - pd2);
                hv[6] = 0; hv[7] = 0;
                *(short8*)(xs + e*RSX) = hv;
            }
        } else {
            // exactly 16 shorts per (e,rep): covers the 64-short row once
            *(short8*)(xs + e*RSX + rep*16 + 0) = pA;
            *(short8*)(xs + e*RSX + rep*16 + 8) = pB;
            if (rep == 0) {
                short8 hv;
                hv[0] = f2bf(ps0 - pd0);
                hv[1] = f2bf(ps1 - pd1);
                hv[2] = f2bf(ps2 - pd2);
                hv[3]=0; hv[4]=0; hv[5]=0; hv[6]=0; hv[7]=0;
                *(short8*)(xs + e*RSX + CIN) = hv;
            }
        }
        barrier_lds_only();

        // ---- issue next tile's gather; lands under GEMM1+GEMM2 ----
        issue(min(tile + STRIDE, NTILES - 1));

        // ---- GEMM1: C1[h][edge] = (wah+wal)^T x + ba ----
        float4v C1[MPW1][4];
        #pragma unroll
        for (int mi = 0; mi < MPW1; ++mi)
            #pragma unroll
            for (int n = 0; n < 4; ++n)
                #pragma unroll
                for (int r = 0; r < 4; ++r) C1[mi][n][r] = bav[mi][r];
        #pragma unroll
        for (int pk = 0; pk < NS1; ++pk)
            #pragma unroll
            for (int n = 0; n < 4; ++n) {
                short8 xh = *(const short8*)(xs + (n*16 + c)*RSX + pk*32 + g*8);
                #pragma unroll
                for (int mi = 0; mi < MPW1; ++mi) {
                    C1[mi][n] = __builtin_amdgcn_mfma_f32_16x16x32_bf16(wah[mi][pk], xh, C1[mi][n], 0,0,0);
                    C1[mi][n] = __builtin_amdgcn_mfma_f32_16x16x32_bf16(wal[mi][pk], xh, C1[mi][n], 0,0,0);
                }
            }
        // epilogue1: relu -> bf16 -> y LDS (lane holds 4 consecutive h)
        #pragma unroll
        for (int mi = 0; mi < MPW1; ++mi) {
            const int mt = mi*4 + w;
            #pragma unroll
            for (int n = 0; n < 4; ++n) {
                short4v hv;
                #pragma unroll
                for (int r = 0; r < 4; ++r)
                    hv[r] = f2bf(fmaxf(C1[mi][n][r], 0.f));
                *(short4v*)(ys + (n*16 + c)*RSY + mt*16 + g*4) = hv;
            }
        }
        barrier_lds_only();

        // ---- GEMM2: C2[o][edge] = (wbh+wbl)^T y + bb ----
        float4v C2[MPW2][4];
        #pragma unroll
        for (int mi = 0; mi < MPW2; ++mi)
            #pragma unroll
            for (int n = 0; n < 4; ++n)
                #pragma unroll
                for (int r = 0; r < 4; ++r) C2[mi][n][r] = bbv[mi][r];
        #pragma unroll
        for (int pk = 0; pk < NS2; ++pk)
            #pragma unroll
            for (int n = 0; n < 4; ++n) {
                short8 yh = *(const short8*)(ys + (n*16 + c)*RSY + pk*32 + g*8);
                #pragma unroll
                for (int mi = 0; mi < MPW2; ++mi) {
                    C2[mi][n] = __builtin_amdgcn_mfma_f32_16x16x32_bf16(wbh[mi][pk], yh, C2[mi][n], 0,0,0);
                    C2[mi][n] = __builtin_amdgcn_mfma_f32_16x16x32_bf16(wbl[mi][pk], yh, C2[mi][n], 0,0,0);
                }
            }
        // epilogue2: per-node max via DPP rotate-reduce (zero DS ops); lanes
        // c<4 of every g-row store channel mt*16 + g*4 + c as bf16.
        #pragma unroll
        for (int mi = 0; mi < MPW2; ++mi) {
            const int mt = mi*4 + w;
            #pragma unroll
            for (int n = 0; n < 4; ++n) {
                float v0 = red16max(C2[mi][n][0]);
                float v1 = red16max(C2[mi][n][1]);
                float v2 = red16max(C2[mi][n][2]);
                float v3 = red16max(C2[mi][n][3]);
                if (c < 4) {
                    float sv = (c == 0) ? v0 : (c == 1) ? v1 : (c == 2) ? v2 : v3;
                    const int node = tile*4 + n;
                    hout[(size_t)node*O + mt*16 + g*4 + c] = (ushort_t)f2bf(fmaxf(sv, 0.f));
                }
            }
        }
        // xs(t+1) writes happen after the NEXT loop head; all waves passed the
        // mid barrier => all finished GEMM1 reads of xs(t). Safe with 2
        // barriers per tile.
    }
}

__global__ void zero_k(float* __restrict__ p, int n)
{
    const int i = blockIdx.x * 256 + threadIdx.x;
    if (i < n) p[i] = 0.f;
}

// batch is SORTED: register accumulation, one atomic per batch-change.
__global__ void pool_k(const ushort_t* __restrict__ h3, const int* __restrict__ batch,
                       float* __restrict__ pooled, float* __restrict__ counts)
{
    const int c    = threadIdx.x & 127;
    const int half = threadIdx.x >> 7;
    const int nbeg = blockIdx.x * 128 + half * 64;
    if (nbeg >= NNODES) return;
    const int nend = min(nbeg + 64, NNODES);

    int   cur = batch[nbeg];
    float acc = 0.f;
    int   runlen = 0;
    for (int n = nbeg; n < nend; ++n) {
        const int b = batch[n];
        if (b != cur) {
            atomicAdd(pooled + cur*128 + c, acc);
            if (c == 0) atomicAdd(counts + cur, (float)runlen);
            acc = 0.f; runlen = 0; cur = b;
        }
        acc += b2f((short)h3[(size_t)n * 128 + c]);
        ++runlen;
    }
    atomicAdd(pooled + cur*128 + c, acc);
    if (c == 0) atomicAdd(counts + cur, (float)runlen);
}

__global__ void reg_k(const float* __restrict__ pooled, const float* __restrict__ counts,
                      const float* __restrict__ wr1, const float* __restrict__ br1,
                      const float* __restrict__ wr2, const float* __restrict__ br2,
                      float* __restrict__ out)
{
    const int b = blockIdx.x;     // 64 blocks
    const int h = threadIdx.x;    // 64 threads = hidden dim
    const float rc = 1.f / fmaxf(counts[b], 1.f);
    float acc = br1[h];
    #pragma unroll
    for (int k = 0; k < 128; ++k)
        acc = fmaf(pooled[b*128 + k] * rc, wr1[k*64 + h], acc);
    float v = acc * wr2[h];
    #pragma unroll
    for (int s = 1; s < 64; s <<= 1)
        v += __shfl_xor(v, s);
    if (h == 0) out[b] = 1.f / (1.f + expf(-(v + br2[0])));
}

extern "C" void kernel_launch(void* const* d_in, const int* in_sizes, int n_in,
                              void* d_out, int out_size, void* d_ws, size_t ws_size,
                              hipStream_t stream)
{
    const float* pos   = (const float*)d_in[0];
    const int*   eidx  = (const int*)d_in[1];    // [2,E]; row 0 = src
    const int*   batch = (const int*)d_in[2];
    // d_in[3] = timestep: unused by the reference
    const float *w1a = (const float*)d_in[4],  *b1a = (const float*)d_in[5];
    const float *w1b = (const float*)d_in[6],  *b1b = (const float*)d_in[7];
    const float *w2a = (const float*)d_in[8],  *b2a = (const float*)d_in[9];
    const float *w2b = (const float*)d_in[10], *b2b = (const float*)d_in[11];
    const float *w3a = (const float*)d_in[12], *b3a = (const float*)d_in[13];
    const float *w3b = (const float*)d_in[14], *b3b = (const float*)d_in[15];
    const float *wr1 = (const float*)d_in[16], *br1 = (const float*)d_in[17];
    const float *wr2 = (const float*)d_in[18], *br2 = (const float*)d_in[19];
    const int* srcArr = eidx;                    // row 0

    // bf16 hidden planes in workspace
    ushort_t* h1 = (ushort_t*)d_ws;                          // N*64 bf16
    ushort_t* h2 = h1 + (size_t)NNODES * 64;                 // N*64 bf16
    ushort_t* h3 = h2 + (size_t)NNODES * 64;                 // N*128 bf16
    float* pooled = (float*)(h3 + (size_t)NNODES * 128);     // B*128 f32
    float* counts = pooled + NBATCH * 128;                   // B
    float* out    = (float*)d_out;

    const dim3 blk(256);
    layer_mfma<3,  64, 64 ><<<1024, blk, 0, stream>>>(nullptr, pos, srcArr, w1a, b1a, w1b, b1b, h1);
    layer_mfma<64, 64, 64 ><<<1024, blk, 0, stream>>>(h1,      pos, srcArr, w2a, b2a, w2b, b2b, h2);
    layer_mfma<64, 128,128><<<1024, blk, 0, stream>>>(h2,      pos, srcArr, w3a, b3a, w3b, b3b, h3);
    zero_k<<<(NBATCH*128 + NBATCH + 255)/256, blk, 0, stream>>>(pooled, NBATCH*128 + NBATCH);
    pool_k<<<(NNODES + 127)/128, blk, 0, stream>>>(h3, batch, pooled, counts);
    reg_k <<<NBATCH, dim3(64), 0, stream>>>(pooled, counts, wr1, br1, wr2, br2, out);
}

// Round 7
// 527.086 us; speedup vs baseline: 1.5066x; 1.5066x over previous
//
#include <hip/hip_runtime.h>
#include <math.h>

#define NNODES 100000
#define NEDGES 1600000
#define NBATCH 64
#define NTILES (NEDGES/64)   // 25000 tiles of 64 edges (4 nodes)

typedef __attribute__((ext_vector_type(8))) short  short8;
typedef __attribute__((ext_vector_type(4))) short  short4v;
typedef __attribute__((ext_vector_type(4))) float  float4v;
typedef unsigned short ushort_t;

__device__ __forceinline__ short f2bf(float f) {           // RTNE fp32->bf16
    unsigned u = __builtin_bit_cast(unsigned, f);
    u += 0x7fffu + ((u >> 16) & 1u);
    return (short)(u >> 16);
}
__device__ __forceinline__ float b2f(short s) {
    unsigned u = ((unsigned)(unsigned short)s) << 16;
    return __builtin_bit_cast(float, u);
}

// max with a row_ror DPP operand: pure-VALU cross-lane (16-lane row rotate).
template<int CTRL>
__device__ __forceinline__ float maxror(float v) {
    int t = __builtin_amdgcn_update_dpp(0, __builtin_bit_cast(int, v),
                                        CTRL, 0xf, 0xf, true);
    return fmaxf(v, __builtin_bit_cast(float, t));
}
__device__ __forceinline__ float red16max(float v) {
    v = maxror<0x128>(v);   // row_ror:8
    v = maxror<0x124>(v);   // row_ror:4
    v = maxror<0x122>(v);   // row_ror:2
    v = maxror<0x121>(v);   // row_ror:1
    return v;               // all 16 lanes of the row now hold the max
}

// Barrier that releases LDS writes but leaves global prefetch loads in
// flight (__syncthreads would drain vmcnt(0) -> the m97 barrier-drain stall).
__device__ __forceinline__ void barrier_lds_only() {
    asm volatile("s_waitcnt lgkmcnt(0)" ::: "memory");
    __builtin_amdgcn_sched_barrier(0);
    __builtin_amdgcn_s_barrier();
    __builtin_amdgcn_sched_barrier(0);
}

// Split-bf16-weights MFMA layer, bf16 activations, register-prefetched gather.
// ONE m-tile per wave (NWAVES = H/16 or O/16 partitioned with n-splitting) so
// per-wave weight fragments fit the 128-reg budget of 4 waves/SIMD without
// spilling (round-6 lesson: (256,4) + 2 m-tiles/wave => scratch explosion).
// A = W^T, B = x^T. D layout (m89): col(=edge)=lane&15, row(=out)=g*4+reg.
template<int CIN, int H, int O, int NWAVES>
__global__ __launch_bounds__(NWAVES*64, 4)
void layer_mfma(const ushort_t* __restrict__ hin, const float* __restrict__ pos,
                const int* __restrict__ srcArr,
                const float* __restrict__ wa, const float* __restrict__ ba,
                const float* __restrict__ wb, const float* __restrict__ bb,
                ushort_t* __restrict__ hout)
{
    constexpr int K1   = CIN + 3;
    constexpr int S1   = ((K1 + 31) / 32) * 32;  // padded K of GEMM1
    constexpr int NS1  = S1 / 32;
    constexpr int NS2  = H / 32;
    constexpr int MT1  = H / 16;                 // m-tiles GEMM1
    constexpr int MT2  = O / 16;                 // m-tiles GEMM2
    constexpr int WPM1 = NWAVES / MT1;           // waves sharing one m-tile
    constexpr int WPM2 = NWAVES / MT2;
    constexpr int NT1  = 4 / WPM1;               // n-subtiles per wave
    constexpr int NT2  = 4 / WPM2;
    constexpr int RSX  = S1 + 8;                 // x row stride (shorts)
    constexpr int RSY  = H + 8;

    __shared__ short smem[64 * RSX + 64 * RSY];
    short* xs = smem;            // [64 edges][x bf16 (S1) | pad]
    short* ys = smem + 64 * RSX; // [64 edges][y bf16 (H)  | pad]

    const int tid  = threadIdx.x;
    const int lane = tid & 63;
    const int w    = tid >> 6;   // wave id
    const int g    = lane >> 4;  // k-group / acc row-group
    const int c    = lane & 15;
    const int e    = tid & 63;   // edge-in-tile this thread stages
    const int rep  = tid >> 6;   // 8-short slice of the row this thread stages
    const int mt1  = w / WPM1;
    const int nb1  = (w % WPM1) * NT1;
    const int mt2  = w / WPM2;
    const int nb2  = (w % WPM2) * NT2;
    const int STRIDE = gridDim.x;

    // Zero LDS once: K-pad columns must read as 0.
    {
        short4v z4 = (short4v)0;
        for (int i = tid; i < (64*RSX + 64*RSY)/4; i += NWAVES*64)
            ((short4v*)smem)[i] = z4;
    }

    // ---- prefetch state: gather rows/pos for tile `targ`, then advance srcN.
    int srcN = srcArr[blockIdx.x * 64 + e];
    short8 pA;
    float ps0, ps1, ps2, pd0, pd1, pd2;
    auto issue = [&](int targ) {
        const int src = srcN;
        if constexpr (CIN == 3) {
            if (rep == 0) {
                ps0 = pos[src*3+0]; ps1 = pos[src*3+1]; ps2 = pos[src*3+2];
                const int node = targ*4 + (e >> 4);
                pd0 = pos[node*3+0]; pd1 = pos[node*3+1]; pd2 = pos[node*3+2];
            }
        } else {
            pA = *(const short8*)(hin + (size_t)src * CIN + rep*8);  // 8 shorts x 8 reps = row
            if (rep == 0) {
                ps0 = pos[src*3+0]; ps1 = pos[src*3+1]; ps2 = pos[src*3+2];
                const int node = targ*4 + (e >> 4);
                pd0 = pos[node*3+0]; pd1 = pos[node*3+1]; pd2 = pos[node*3+2];
            }
        }
        const int tn = min(targ + STRIDE, NTILES - 1);
        srcN = srcArr[tn*64 + e];
    };
    issue(blockIdx.x);   // tile0's gather in flight under the weight build

    // ---- per-wave weight fragments: ONLY this wave's m-tile ----
    short8 wah[NS1], wal[NS1];
    float  bav[4];
    {
        const int h = mt1*16 + c;
        #pragma unroll
        for (int pk = 0; pk < NS1; ++pk) {
            short8 fh, fl;
            #pragma unroll
            for (int j = 0; j < 8; ++j) {
                const int k = pk*32 + g*8 + j;
                float f = (k < K1) ? wa[k*H + h] : 0.f;
                short hi = f2bf(f);
                fh[j] = hi;
                fl[j] = f2bf(f - b2f(hi));
            }
            wah[pk] = fh; wal[pk] = fl;
        }
        #pragma unroll
        for (int r = 0; r < 4; ++r) bav[r] = ba[mt1*16 + g*4 + r];
    }
    short8 wbh[NS2], wbl[NS2];
    float  bbv[4];
    {
        const int o = mt2*16 + c;
        #pragma unroll
        for (int pk = 0; pk < NS2; ++pk) {
            short8 fh, fl;
            #pragma unroll
            for (int j = 0; j < 8; ++j) {
                const int k = pk*32 + g*8 + j;   // k < H always
                float f = wb[k*O + o];
                short hi = f2bf(f);
                fh[j] = hi;
                fl[j] = f2bf(f - b2f(hi));
            }
            wbh[pk] = fh; wbl[pk] = fl;
        }
        #pragma unroll
        for (int r = 0; r < 4; ++r) bbv[r] = bb[mt2*16 + g*4 + r];
    }
    __syncthreads();

    for (int tile = blockIdx.x; tile < NTILES; tile += STRIDE) {
        // ---- stage x(tile) from prefetched regs ----
        if constexpr (CIN == 3) {
            if (rep == 0) {
                short8 hv;
                hv[0] = f2bf(ps0); hv[1] = f2bf(ps1); hv[2] = f2bf(ps2);
                hv[3] = f2bf(ps0 - pd0);
                hv[4] = f2bf(ps1 - pd1);
                hv[5] = f2bf(ps2 - pd2);
                hv[6] = 0; hv[7] = 0;
                *(short8*)(xs + e*RSX) = hv;
            }
        } else {
            *(short8*)(xs + e*RSX + rep*8) = pA;   // exact row coverage
            if (rep == 0) {
                short8 hv;
                hv[0] = f2bf(ps0 - pd0);
                hv[1] = f2bf(ps1 - pd1);
                hv[2] = f2bf(ps2 - pd2);
                hv[3]=0; hv[4]=0; hv[5]=0; hv[6]=0; hv[7]=0;
                *(short8*)(xs + e*RSX + CIN) = hv;
            }
        }
        barrier_lds_only();

        // ---- issue next tile's gather; lands under GEMM1+GEMM2 ----
        issue(min(tile + STRIDE, NTILES - 1));

        // ---- GEMM1: C1[h][edge] = (wah+wal)^T x + ba  (this wave: mt1, nb1..) ----
        float4v C1[NT1];
        #pragma unroll
        for (int ni = 0; ni < NT1; ++ni)
            #pragma unroll
            for (int r = 0; r < 4; ++r) C1[ni][r] = bav[r];
        #pragma unroll
        for (int pk = 0; pk < NS1; ++pk)
            #pragma unroll
            for (int ni = 0; ni < NT1; ++ni) {
                short8 xh = *(const short8*)(xs + ((nb1+ni)*16 + c)*RSX + pk*32 + g*8);
                C1[ni] = __builtin_amdgcn_mfma_f32_16x16x32_bf16(wah[pk], xh, C1[ni], 0,0,0);
                C1[ni] = __builtin_amdgcn_mfma_f32_16x16x32_bf16(wal[pk], xh, C1[ni], 0,0,0);
            }
        // epilogue1: relu -> bf16 -> y LDS (lane holds 4 consecutive h)
        #pragma unroll
        for (int ni = 0; ni < NT1; ++ni) {
            short4v hv;
            #pragma unroll
            for (int r = 0; r < 4; ++r)
                hv[r] = f2bf(fmaxf(C1[ni][r], 0.f));
            *(short4v*)(ys + ((nb1+ni)*16 + c)*RSY + mt1*16 + g*4) = hv;
        }
        barrier_lds_only();

        // ---- GEMM2: C2[o][edge] = (wbh+wbl)^T y + bb  (this wave: mt2, nb2..) ----
        float4v C2[NT2];
        #pragma unroll
        for (int ni = 0; ni < NT2; ++ni)
            #pragma unroll
            for (int r = 0; r < 4; ++r) C2[ni][r] = bbv[r];
        #pragma unroll
        for (int pk = 0; pk < NS2; ++pk)
            #pragma unroll
            for (int ni = 0; ni < NT2; ++ni) {
                short8 yh = *(const short8*)(ys + ((nb2+ni)*16 + c)*RSY + pk*32 + g*8);
                C2[ni] = __builtin_amdgcn_mfma_f32_16x16x32_bf16(wbh[pk], yh, C2[ni], 0,0,0);
                C2[ni] = __builtin_amdgcn_mfma_f32_16x16x32_bf16(wbl[pk], yh, C2[ni], 0,0,0);
            }
        // epilogue2: per-node max via DPP rotate-reduce; lanes c<4 of each
        // g-row store channel mt2*16 + g*4 + c as bf16.
        #pragma unroll
        for (int ni = 0; ni < NT2; ++ni) {
            float v0 = red16max(C2[ni][0]);
            float v1 = red16max(C2[ni][1]);
            float v2 = red16max(C2[ni][2]);
            float v3 = red16max(C2[ni][3]);
            if (c < 4) {
                float sv = (c == 0) ? v0 : (c == 1) ? v1 : (c == 2) ? v2 : v3;
                const int node = tile*4 + nb2 + ni;
                hout[(size_t)node*O + mt2*16 + g*4 + c] = (ushort_t)f2bf(fmaxf(sv, 0.f));
            }
        }
        // 2 barriers/tile is safe: a wave reaches stage(t+1) only after epi2(t),
        // and barrier-1(t+1) orders xs writes vs all waves' GEMM1(t) reads.
    }
}

__global__ void zero_k(float* __restrict__ p, int n)
{
    const int i = blockIdx.x * 256 + threadIdx.x;
    if (i < n) p[i] = 0.f;
}

// batch is SORTED: register accumulation, one atomic per batch-change.
__global__ void pool_k(const ushort_t* __restrict__ h3, const int* __restrict__ batch,
                       float* __restrict__ pooled, float* __restrict__ counts)
{
    const int c    = threadIdx.x & 127;
    const int half = threadIdx.x >> 7;
    const int nbeg = blockIdx.x * 128 + half * 64;
    if (nbeg >= NNODES) return;
    const int nend = min(nbeg + 64, NNODES);

    int   cur = batch[nbeg];
    float acc = 0.f;
    int   runlen = 0;
    for (int n = nbeg; n < nend; ++n) {
        const int b = batch[n];
        if (b != cur) {
            atomicAdd(pooled + cur*128 + c, acc);
            if (c == 0) atomicAdd(counts + cur, (float)runlen);
            acc = 0.f; runlen = 0; cur = b;
        }
        acc += b2f((short)h3[(size_t)n * 128 + c]);
        ++runlen;
    }
    atomicAdd(pooled + cur*128 + c, acc);
    if (c == 0) atomicAdd(counts + cur, (float)runlen);
}

__global__ void reg_k(const float* __restrict__ pooled, const float* __restrict__ counts,
                      const float* __restrict__ wr1, const float* __restrict__ br1,
                      const float* __restrict__ wr2, const float* __restrict__ br2,
                      float* __restrict__ out)
{
    const int b = blockIdx.x;     // 64 blocks
    const int h = threadIdx.x;    // 64 threads = hidden dim
    const float rc = 1.f / fmaxf(counts[b], 1.f);
    float acc = br1[h];
    #pragma unroll
    for (int k = 0; k < 128; ++k)
        acc = fmaf(pooled[b*128 + k] * rc, wr1[k*64 + h], acc);
    float v = acc * wr2[h];
    #pragma unroll
    for (int s = 1; s < 64; s <<= 1)
        v += __shfl_xor(v, s);
    if (h == 0) out[b] = 1.f / (1.f + expf(-(v + br2[0])));
}

extern "C" void kernel_launch(void* const* d_in, const int* in_sizes, int n_in,
                              void* d_out, int out_size, void* d_ws, size_t ws_size,
                              hipStream_t stream)
{
    const float* pos   = (const float*)d_in[0];
    const int*   eidx  = (const int*)d_in[1];    // [2,E]; row 0 = src
    const int*   batch = (const int*)d_in[2];
    // d_in[3] = timestep: unused by the reference
    const float *w1a = (const float*)d_in[4],  *b1a = (const float*)d_in[5];
    const float *w1b = (const float*)d_in[6],  *b1b = (const float*)d_in[7];
    const float *w2a = (const float*)d_in[8],  *b2a = (const float*)d_in[9];
    const float *w2b = (const float*)d_in[10], *b2b = (const float*)d_in[11];
    const float *w3a = (const float*)d_in[12], *b3a = (const float*)d_in[13];
    const float *w3b = (const float*)d_in[14], *b3b = (const float*)d_in[15];
    const float *wr1 = (const float*)d_in[16], *br1 = (const float*)d_in[17];
    const float *wr2 = (const float*)d_in[18], *br2 = (const float*)d_in[19];
    const int* srcArr = eidx;                    // row 0

    // bf16 hidden planes in workspace
    ushort_t* h1 = (ushort_t*)d_ws;                          // N*64 bf16
    ushort_t* h2 = h1 + (size_t)NNODES * 64;                 // N*64 bf16
    ushort_t* h3 = h2 + (size_t)NNODES * 64;                 // N*128 bf16
    float* pooled = (float*)(h3 + (size_t)NNODES * 128);     // B*128 f32
    float* counts = pooled + NBATCH * 128;                   // B
    float* out    = (float*)d_out;

    // L1: 4 waves (tiny weights), 4 blocks/CU. L2/L3: 8 waves, one m-tile per
    // wave, 2 blocks/CU -> 16 waves/CU everywhere, 128-reg budget respected.
    layer_mfma<3,  64, 64, 4><<<1024, dim3(256), 0, stream>>>(nullptr, pos, srcArr, w1a, b1a, w1b, b1b, h1);
    layer_mfma<64, 64, 64, 8><<< 512, dim3(512), 0, stream>>>(h1,      pos, srcArr, w2a, b2a, w2b, b2b, h2);
    layer_mfma<64, 128,128,8><<< 512, dim3(512), 0, stream>>>(h2,      pos, srcArr, w3a, b3a, w3b, b3b, h3);
    zero_k<<<(NBATCH*128 + NBATCH + 255)/256, dim3(256), 0, stream>>>(pooled, NBATCH*128 + NBATCH);
    pool_k<<<(NNODES + 127)/128, dim3(256), 0, stream>>>(h3, batch, pooled, counts);
    reg_k <<<NBATCH, dim3(64), 0, stream>>>(pooled, counts, wr1, br1, wr2, br2, out);
}

// Round 8
// 368.800 us; speedup vs baseline: 2.1532x; 1.4292x over previous
//
#include <hip/hip_runtime.h>
#include <math.h>

#define NNODES 100000
#define NEDGES 1600000
#define NBATCH 64
#define NTILES (NEDGES/64)   // 25000 tiles of 64 edges (4 nodes)

typedef __attribute__((ext_vector_type(8))) short  short8;
typedef __attribute__((ext_vector_type(4))) short  short4v;
typedef __attribute__((ext_vector_type(2))) unsigned int uint2v;
typedef __attribute__((ext_vector_type(4))) float  float4v;
typedef unsigned short ushort_t;

__device__ __forceinline__ short f2bf(float f) {           // RTNE fp32->bf16
    unsigned u = __builtin_bit_cast(unsigned, f);
    u += 0x7fffu + ((u >> 16) & 1u);
    return (short)(u >> 16);
}
__device__ __forceinline__ float b2f(short s) {
    unsigned u = ((unsigned)(unsigned short)s) << 16;
    return __builtin_bit_cast(float, u);
}
// 2×f32 -> packed 2×bf16 in one VALU op (lo -> low 16 bits).
__device__ __forceinline__ unsigned cvt_pk_bf16(float lo, float hi) {
    unsigned r;
    asm("v_cvt_pk_bf16_f32 %0, %1, %2" : "=v"(r) : "v"(lo), "v"(hi));
    return r;
}

// Barrier that releases LDS writes but leaves global prefetch loads in
// flight (__syncthreads would drain vmcnt(0) -> the m97 barrier-drain stall).
__device__ __forceinline__ void barrier_lds_only() {
    asm volatile("s_waitcnt lgkmcnt(0)" ::: "memory");
    __builtin_amdgcn_sched_barrier(0);
    __builtin_amdgcn_s_barrier();
    __builtin_amdgcn_sched_barrier(0);
}

// bf16-weights MFMA layer, bf16 activations, register-prefetched gather.
// GEMM1: A = W^T (M = hidden), B = x^T (N = edges); D col=edge, row=h ->
//   epilogue writes ys[edge][h] as packed 8B (cvt_pk).
// GEMM2 FLIPPED: A = y (M = edges), B = W (N = out-channels); D row=edge,
//   col=out -> the 16-edge segment-max is 3 lane-local reg maxes + 2
//   shfl_xor (cheap), replacing the round-7 DPP storm (the VALU bottleneck).
// Weights live in per-wave registers; only activations stream through LDS.
template<int CIN, int H, int O, int NWAVES, int MINW>
__global__ __launch_bounds__(NWAVES*64, MINW)
void layer_mfma(const ushort_t* __restrict__ hin, const float* __restrict__ pos,
                const int* __restrict__ srcArr,
                const float* __restrict__ wa, const float* __restrict__ ba,
                const float* __restrict__ wb, const float* __restrict__ bb,
                ushort_t* __restrict__ hout)
{
    constexpr int K1   = CIN + 3;
    constexpr int S1   = ((K1 + 31) / 32) * 32;  // padded K of GEMM1
    constexpr int NS1  = S1 / 32;
    constexpr int NS2  = H / 32;
    constexpr int MT1  = H / 16;                 // m-tiles GEMM1
    constexpr int WPM1 = NWAVES / MT1 > 0 ? NWAVES / MT1 : 1;
    constexpr int NT1  = 4 / WPM1;               // n-subtiles per wave, GEMM1
    constexpr int NTIL2= O / 16;                 // n-tiles GEMM2 (channels)
    constexpr int WPN2 = NWAVES / NTIL2 > 0 ? NWAVES / NTIL2 : 1;
    constexpr int MT2v = 4 / WPN2;               // m-tiles (nodes) per wave
    constexpr int RSX  = S1 + 8;                 // x row stride (shorts)
    constexpr int RSY  = H + 8;

    __shared__ short smem[64 * RSX + 64 * RSY];
    short* xs = smem;            // [64 edges][x bf16 (S1) | pad]
    short* ys = smem + 64 * RSX; // [64 edges][y bf16 (H)  | pad]

    const int tid  = threadIdx.x;
    const int lane = tid & 63;
    const int w    = tid >> 6;   // wave id
    const int g    = lane >> 4;  // k-group / row-group
    const int c    = lane & 15;
    const int e    = tid & 63;   // edge-in-tile this thread stages
    const int rep  = tid >> 6;   // 8-short slice of the row this thread stages
    const int mt1  = w / WPM1;           // GEMM1 m-tile (h block)
    const int nb1  = (w % WPM1) * NT1;   // GEMM1 n-subtile base
    const int wnb  = w / WPN2;           // GEMM2 n-tile (channel block)
    const int msub = (w % WPN2) * MT2v;  // GEMM2 m-tile (node) base
    const int STRIDE = gridDim.x;

    // Zero LDS once: K-pad columns must read as 0.
    {
        short4v z4 = (short4v)0;
        for (int i = tid; i < (64*RSX + 64*RSY)/4; i += NWAVES*64)
            ((short4v*)smem)[i] = z4;
    }

    // ---- prefetch state: gather rows/pos for tile `targ`, then advance srcN.
    int srcN = srcArr[blockIdx.x * 64 + e];
    short8 pA;
    float ps0, ps1, ps2, pd0, pd1, pd2;
    auto issue = [&](int targ) {
        const int src = srcN;
        if constexpr (CIN == 3) {
            if (rep == 0) {
                ps0 = pos[src*3+0]; ps1 = pos[src*3+1]; ps2 = pos[src*3+2];
                const int node = targ*4 + (e >> 4);
                pd0 = pos[node*3+0]; pd1 = pos[node*3+1]; pd2 = pos[node*3+2];
            }
        } else {
            pA = *(const short8*)(hin + (size_t)src * CIN + rep*8);
            if (rep == 0) {
                ps0 = pos[src*3+0]; ps1 = pos[src*3+1]; ps2 = pos[src*3+2];
                const int node = targ*4 + (e >> 4);
                pd0 = pos[node*3+0]; pd1 = pos[node*3+1]; pd2 = pos[node*3+2];
            }
        }
        const int tn = min(targ + STRIDE, NTILES - 1);
        srcN = srcArr[tn*64 + e];
    };
    issue(blockIdx.x);   // tile0's gather in flight under the weight build

    // ---- per-wave weight fragments (single bf16 plane) ----
    short8 wah[NS1];
    float  bav[4];
    {
        const int h = mt1*16 + c;
        #pragma unroll
        for (int pk = 0; pk < NS1; ++pk) {
            short8 fh;
            #pragma unroll
            for (int j = 0; j < 8; ++j) {
                const int k = pk*32 + g*8 + j;
                fh[j] = (k < K1) ? f2bf(wa[k*H + h]) : (short)0;
            }
            wah[pk] = fh;
        }
        #pragma unroll
        for (int r = 0; r < 4; ++r) bav[r] = ba[mt1*16 + g*4 + r];
    }
    short8 wbh[NS2];
    float  bbsc;        // GEMM2 flipped: bias depends only on col (= lane c)
    {
        const int o = wnb*16 + c;
        #pragma unroll
        for (int pk = 0; pk < NS2; ++pk) {
            short8 fh;
            #pragma unroll
            for (int j = 0; j < 8; ++j) {
                const int k = pk*32 + g*8 + j;   // k < H always
                fh[j] = f2bf(wb[k*O + o]);
            }
            wbh[pk] = fh;
        }
        bbsc = bb[o];
    }
    __syncthreads();

    for (int tile = blockIdx.x; tile < NTILES; tile += STRIDE) {
        // ---- stage x(tile) from prefetched regs ----
        if constexpr (CIN == 3) {
            if (rep == 0) {
                short8 hv;
                hv[0] = f2bf(ps0); hv[1] = f2bf(ps1); hv[2] = f2bf(ps2);
                hv[3] = f2bf(ps0 - pd0);
                hv[4] = f2bf(ps1 - pd1);
                hv[5] = f2bf(ps2 - pd2);
                hv[6] = 0; hv[7] = 0;
                *(short8*)(xs + e*RSX) = hv;
            }
        } else {
            *(short8*)(xs + e*RSX + rep*8) = pA;   // exact row coverage
            if (rep == 0) {
                short8 hv;
                hv[0] = f2bf(ps0 - pd0);
                hv[1] = f2bf(ps1 - pd1);
                hv[2] = f2bf(ps2 - pd2);
                hv[3]=0; hv[4]=0; hv[5]=0; hv[6]=0; hv[7]=0;
                *(short8*)(xs + e*RSX + CIN) = hv;
            }
        }
        barrier_lds_only();

        // ---- issue next tile's gather; lands under GEMM1+GEMM2 ----
        issue(min(tile + STRIDE, NTILES - 1));

        // ---- GEMM1: C1[h][edge] = wa^T x + ba ----
        {
            float4v C1[NT1];
            #pragma unroll
            for (int ni = 0; ni < NT1; ++ni)
                #pragma unroll
                for (int r = 0; r < 4; ++r) C1[ni][r] = bav[r];
            #pragma unroll
            for (int pk = 0; pk < NS1; ++pk)
                #pragma unroll
                for (int ni = 0; ni < NT1; ++ni) {
                    short8 xh = *(const short8*)(xs + ((nb1+ni)*16 + c)*RSX + pk*32 + g*8);
                    C1[ni] = __builtin_amdgcn_mfma_f32_16x16x32_bf16(wah[pk], xh, C1[ni], 0,0,0);
                }
            // epilogue1: relu -> packed bf16 (cvt_pk) -> ys[edge][h]
            #pragma unroll
            for (int ni = 0; ni < NT1; ++ni) {
                uint2v pv;
                pv[0] = cvt_pk_bf16(fmaxf(C1[ni][0], 0.f), fmaxf(C1[ni][1], 0.f));
                pv[1] = cvt_pk_bf16(fmaxf(C1[ni][2], 0.f), fmaxf(C1[ni][3], 0.f));
                *(uint2v*)(ys + ((nb1+ni)*16 + c)*RSY + mt1*16 + g*4) = pv;
            }
        }
        barrier_lds_only();

        // ---- GEMM2 (flipped): C2[edge][o] = y wb + bb ----
        float4v C2[MT2v];
        #pragma unroll
        for (int mi = 0; mi < MT2v; ++mi)
            #pragma unroll
            for (int r = 0; r < 4; ++r) C2[mi][r] = bbsc;
        #pragma unroll
        for (int pk = 0; pk < NS2; ++pk)
            #pragma unroll
            for (int mi = 0; mi < MT2v; ++mi) {
                short8 yh = *(const short8*)(ys + ((msub+mi)*16 + c)*RSY + pk*32 + g*8);
                C2[mi] = __builtin_amdgcn_mfma_f32_16x16x32_bf16(yh, wbh[pk], C2[mi], 0,0,0);
            }
        // epilogue2: rows are edges -> 3 lane-local maxes + xor32 + xor16,
        // then lanes 0..15 store 16 consecutive channels for this node.
        #pragma unroll
        for (int mi = 0; mi < MT2v; ++mi) {
            float m = fmaxf(fmaxf(C2[mi][0], C2[mi][1]),
                            fmaxf(C2[mi][2], C2[mi][3]));
            m = fmaxf(m, __shfl_xor(m, 32));
            m = fmaxf(m, __shfl_xor(m, 16));
            if (lane < 16) {
                const int node = tile*4 + msub + mi;
                hout[(size_t)node*O + wnb*16 + lane] = (ushort_t)f2bf(fmaxf(m, 0.f));
            }
        }
        // 2 barriers/tile is safe: a wave reaches stage(t+1) only after epi2(t);
        // barrier-1(t+1) orders xs writes vs all waves' GEMM1(t) reads, and
        // between barriers GEMM2 touches only ys.
    }
}

__global__ void zero_k(float* __restrict__ p, int n)
{
    const int i = blockIdx.x * 256 + threadIdx.x;
    if (i < n) p[i] = 0.f;
}

// batch is SORTED: register accumulation, one atomic per batch-change.
__global__ void pool_k(const ushort_t* __restrict__ h3, const int* __restrict__ batch,
                       float* __restrict__ pooled, float* __restrict__ counts)
{
    const int c    = threadIdx.x & 127;
    const int half = threadIdx.x >> 7;
    const int nbeg = blockIdx.x * 128 + half * 64;
    if (nbeg >= NNODES) return;
    const int nend = min(nbeg + 64, NNODES);

    int   cur = batch[nbeg];
    float acc = 0.f;
    int   runlen = 0;
    for (int n = nbeg; n < nend; ++n) {
        const int b = batch[n];
        if (b != cur) {
            atomicAdd(pooled + cur*128 + c, acc);
            if (c == 0) atomicAdd(counts + cur, (float)runlen);
            acc = 0.f; runlen = 0; cur = b;
        }
        acc += b2f((short)h3[(size_t)n * 128 + c]);
        ++runlen;
    }
    atomicAdd(pooled + cur*128 + c, acc);
    if (c == 0) atomicAdd(counts + cur, (float)runlen);
}

__global__ void reg_k(const float* __restrict__ pooled, const float* __restrict__ counts,
                      const float* __restrict__ wr1, const float* __restrict__ br1,
                      const float* __restrict__ wr2, const float* __restrict__ br2,
                      float* __restrict__ out)
{
    const int b = blockIdx.x;     // 64 blocks
    const int h = threadIdx.x;    // 64 threads = hidden dim
    const float rc = 1.f / fmaxf(counts[b], 1.f);
    float acc = br1[h];
    #pragma unroll
    for (int k = 0; k < 128; ++k)
        acc = fmaf(pooled[b*128 + k] * rc, wr1[k*64 + h], acc);
    float v = acc * wr2[h];
    #pragma unroll
    for (int s = 1; s < 64; s <<= 1)
        v += __shfl_xor(v, s);
    if (h == 0) out[b] = 1.f / (1.f + expf(-(v + br2[0])));
}

extern "C" void kernel_launch(void* const* d_in, const int* in_sizes, int n_in,
                              void* d_out, int out_size, void* d_ws, size_t ws_size,
                              hipStream_t stream)
{
    const float* pos   = (const float*)d_in[0];
    const int*   eidx  = (const int*)d_in[1];    // [2,E]; row 0 = src
    const int*   batch = (const int*)d_in[2];
    // d_in[3] = timestep: unused by the reference
    const float *w1a = (const float*)d_in[4],  *b1a = (const float*)d_in[5];
    const float *w1b = (const float*)d_in[6],  *b1b = (const float*)d_in[7];
    const float *w2a = (const float*)d_in[8],  *b2a = (const float*)d_in[9];
    const float *w2b = (const float*)d_in[10], *b2b = (const float*)d_in[11];
    const float *w3a = (const float*)d_in[12], *b3a = (const float*)d_in[13];
    const float *w3b = (const float*)d_in[14], *b3b = (const float*)d_in[15];
    const float *wr1 = (const float*)d_in[16], *br1 = (const float*)d_in[17];
    const float *wr2 = (const float*)d_in[18], *br2 = (const float*)d_in[19];
    const int* srcArr = eidx;                    // row 0

    // bf16 hidden planes in workspace
    ushort_t* h1 = (ushort_t*)d_ws;                          // N*64 bf16
    ushort_t* h2 = h1 + (size_t)NNODES * 64;                 // N*64 bf16
    ushort_t* h3 = h2 + (size_t)NNODES * 64;                 // N*128 bf16
    float* pooled = (float*)(h3 + (size_t)NNODES * 128);     // B*128 f32
    float* counts = pooled + NBATCH * 128;                   // B
    float* out    = (float*)d_out;

    // L1: 4 waves, 8 blocks/CU (64-reg budget). L2/L3: 8 waves, 3 blocks/CU
    // (85-reg budget) -> 24 waves/CU. Grids sized to exact residency.
    layer_mfma<3,  64, 64, 4, 8><<<2048, dim3(256), 0, stream>>>(nullptr, pos, srcArr, w1a, b1a, w1b, b1b, h1);
    layer_mfma<64, 64, 64, 8, 6><<< 768, dim3(512), 0, stream>>>(h1,      pos, srcArr, w2a, b2a, w2b, b2b, h2);
    layer_mfma<64, 128,128,8, 6><<< 768, dim3(512), 0, stream>>>(h2,      pos, srcArr, w3a, b3a, w3b, b3b, h3);
    zero_k<<<(NBATCH*128 + NBATCH + 255)/256, dim3(256), 0, stream>>>(pooled, NBATCH*128 + NBATCH);
    pool_k<<<(NNODES + 127)/128, dim3(256), 0, stream>>>(h3, batch, pooled, counts);
    reg_k <<<NBATCH, dim3(64), 0, stream>>>(pooled, counts, wr1, br1, wr2, br2, out);
}

// Round 9
// 357.388 us; speedup vs baseline: 2.2219x; 1.0319x over previous
//
#include <hip/hip_runtime.h>
#include <math.h>

#define NNODES 100000
#define NEDGES 1600000
#define NBATCH 64
#define NTILES (NEDGES/64)   // 25000 tiles of 64 edges (4 nodes)

typedef __attribute__((ext_vector_type(8))) short  short8;
typedef __attribute__((ext_vector_type(4))) short  short4v;
typedef __attribute__((ext_vector_type(2))) unsigned int uint2v;
typedef __attribute__((ext_vector_type(4))) float  float4v;
typedef unsigned short ushort_t;

__device__ __forceinline__ short f2bf(float f) {           // RTNE fp32->bf16
    unsigned u = __builtin_bit_cast(unsigned, f);
    u += 0x7fffu + ((u >> 16) & 1u);
    return (short)(u >> 16);
}
__device__ __forceinline__ float b2f(short s) {
    unsigned u = ((unsigned)(unsigned short)s) << 16;
    return __builtin_bit_cast(float, u);
}
// 2×f32 -> packed 2×bf16 in one VALU op (lo -> low 16 bits).
__device__ __forceinline__ unsigned cvt_pk_bf16(float lo, float hi) {
    unsigned r;
    asm("v_cvt_pk_bf16_f32 %0, %1, %2" : "=v"(r) : "v"(lo), "v"(hi));
    return r;
}
// max over the 4 16-lane groups {c, c+16, c+32, c+48} without DS ops:
// permlane16/32 swaps are VALU (keeps the saturated LDS pipe free).
__device__ __forceinline__ float red_groups_max(float m) {
    unsigned a = __builtin_bit_cast(unsigned, m), b = a;
    asm("v_permlane16_swap_b32 %0, %1" : "+v"(a), "+v"(b));
    m = fmaxf(__builtin_bit_cast(float, a), __builtin_bit_cast(float, b));
    a = __builtin_bit_cast(unsigned, m); b = a;
    asm("v_permlane32_swap_b32 %0, %1" : "+v"(a), "+v"(b));
    return fmaxf(__builtin_bit_cast(float, a), __builtin_bit_cast(float, b));
}

// Barrier that releases LDS writes but leaves global prefetch loads in
// flight (__syncthreads would drain vmcnt(0) -> the m97 barrier-drain stall).
__device__ __forceinline__ void barrier_lds_only() {
    asm volatile("s_waitcnt lgkmcnt(0)" ::: "memory");
    __builtin_amdgcn_sched_barrier(0);
    __builtin_amdgcn_s_barrier();
    __builtin_amdgcn_sched_barrier(0);
}

// bf16 MFMA layer, LDS-traffic-minimized: per-wave output blocks are 32 WIDE
// (2 m-tiles GEMM1 / 2 channel-frags GEMM2) so every ds_read_b128 feeds TWO
// MFMAs -> LDS read bytes halve vs 16-wide (round-8 bottleneck: per-CU LDS
// pipe saturated at ~11k cyc/tile). Epilogue-2 cross-lane max uses
// v_permlane*_swap (VALU) instead of shfl_xor (DS bpermute).
// GEMM1: A = W^T (M=h), B = x^T (N=edges). GEMM2 flipped: A = y (M=edges),
// B = W (N=channels). D layout (m89): col=lane&15, row=(lane>>4)*4+reg.
template<int CIN, int H, int O, int NWAVES, int MINW>
__global__ __launch_bounds__(NWAVES*64, MINW)
void layer_mfma(const ushort_t* __restrict__ hin, const float* __restrict__ pos,
                const int* __restrict__ srcArr,
                const float* __restrict__ wa, const float* __restrict__ ba,
                const float* __restrict__ wb, const float* __restrict__ bb,
                ushort_t* __restrict__ hout)
{
    constexpr int K1   = CIN + 3;
    constexpr int S1   = ((K1 + 31) / 32) * 32;  // padded K of GEMM1
    constexpr int NS1  = S1 / 32;
    constexpr int NS2  = H / 32;
    // GEMM1 wave split: 32-wide h-block x edge-group
    constexpr int HB1  = H / 32;
    constexpr int EH1  = NWAVES / HB1;
    constexpr int E1   = 64 / EH1;               // edges per group
    constexpr int NT1  = E1 / 16;
    // GEMM2 wave split: 32-wide channel-block x edge-group
    constexpr int CB2  = O / 32;
    constexpr int EH2  = NWAVES / CB2;
    constexpr int E2   = 64 / EH2;
    constexpr int MT2  = E2 / 16;
    constexpr int RSX  = S1 + 8;                 // x row stride (shorts)
    constexpr int RSY  = H + 8;

    __shared__ short smem[64 * RSX + 64 * RSY];
    short* xs = smem;            // [64 edges][x bf16 (S1) | pad]
    short* ys = smem + 64 * RSX; // [64 edges][y bf16 (H)  | pad]

    const int tid  = threadIdx.x;
    const int lane = tid & 63;
    const int w    = tid >> 6;   // wave id
    const int g    = lane >> 4;  // k-group / row-group
    const int c    = lane & 15;
    const int e    = tid & 63;   // edge-in-tile this thread stages
    const int rep  = tid >> 6;   // 8-short slice of the row this thread stages
    const int hb   = w / EH1;    // GEMM1 h-block (32 wide)
    const int eg1  = w % EH1;    // GEMM1 edge group
    const int cb2  = w / EH2;    // GEMM2 channel block (32 wide)
    const int eg2  = w % EH2;    // GEMM2 edge group
    const int STRIDE = gridDim.x;

    // Zero LDS once: K-pad columns must read as 0.
    {
        short4v z4 = (short4v)0;
        for (int i = tid; i < (64*RSX + 64*RSY)/4; i += NWAVES*64)
            ((short4v*)smem)[i] = z4;
    }

    // ---- prefetch state: gather rows/pos for tile `targ`, then advance srcN.
    int srcN = srcArr[blockIdx.x * 64 + e];
    short8 pA;
    float ps0, ps1, ps2, pd0, pd1, pd2;
    auto issue = [&](int targ) {
        const int src = srcN;
        if constexpr (CIN == 3) {
            if (rep == 0) {
                ps0 = pos[src*3+0]; ps1 = pos[src*3+1]; ps2 = pos[src*3+2];
                const int node = targ*4 + (e >> 4);
                pd0 = pos[node*3+0]; pd1 = pos[node*3+1]; pd2 = pos[node*3+2];
            }
        } else {
            pA = *(const short8*)(hin + (size_t)src * CIN + rep*8);
            if (rep == 0) {
                ps0 = pos[src*3+0]; ps1 = pos[src*3+1]; ps2 = pos[src*3+2];
                const int node = targ*4 + (e >> 4);
                pd0 = pos[node*3+0]; pd1 = pos[node*3+1]; pd2 = pos[node*3+2];
            }
        }
        const int tn = min(targ + STRIDE, NTILES - 1);
        srcN = srcArr[tn*64 + e];
    };
    issue(blockIdx.x);   // tile0's gather in flight under the weight build

    // ---- per-wave weight fragments: 2 m-tiles (GEMM1), 2 ch-frags (GEMM2) ----
    short8 wah[2][NS1];
    float  bav[2][4];
    #pragma unroll
    for (int mt = 0; mt < 2; ++mt) {
        const int h = hb*32 + mt*16 + c;
        #pragma unroll
        for (int pk = 0; pk < NS1; ++pk) {
            short8 fh;
            #pragma unroll
            for (int j = 0; j < 8; ++j) {
                const int k = pk*32 + g*8 + j;
                fh[j] = (k < K1) ? f2bf(wa[k*H + h]) : (short)0;
            }
            wah[mt][pk] = fh;
        }
        #pragma unroll
        for (int r = 0; r < 4; ++r) bav[mt][r] = ba[hb*32 + mt*16 + g*4 + r];
    }
    short8 wbh[2][NS2];
    float  bbsc[2];
    #pragma unroll
    for (int cb = 0; cb < 2; ++cb) {
        const int o = cb2*32 + cb*16 + c;
        #pragma unroll
        for (int pk = 0; pk < NS2; ++pk) {
            short8 fh;
            #pragma unroll
            for (int j = 0; j < 8; ++j) {
                const int k = pk*32 + g*8 + j;   // k < H always
                fh[j] = f2bf(wb[k*O + o]);
            }
            wbh[cb][pk] = fh;
        }
        bbsc[cb] = bb[o];
    }
    __syncthreads();

    for (int tile = blockIdx.x; tile < NTILES; tile += STRIDE) {
        // ---- stage x(tile) from prefetched regs ----
        if constexpr (CIN == 3) {
            if (rep == 0) {
                short8 hv;
                hv[0] = f2bf(ps0); hv[1] = f2bf(ps1); hv[2] = f2bf(ps2);
                hv[3] = f2bf(ps0 - pd0);
                hv[4] = f2bf(ps1 - pd1);
                hv[5] = f2bf(ps2 - pd2);
                hv[6] = 0; hv[7] = 0;
                *(short8*)(xs + e*RSX) = hv;
            }
        } else {
            *(short8*)(xs + e*RSX + rep*8) = pA;   // exact row coverage
            if (rep == 0) {
                short8 hv;
                hv[0] = f2bf(ps0 - pd0);
                hv[1] = f2bf(ps1 - pd1);
                hv[2] = f2bf(ps2 - pd2);
                hv[3]=0; hv[4]=0; hv[5]=0; hv[6]=0; hv[7]=0;
                *(short8*)(xs + e*RSX + CIN) = hv;
            }
        }
        barrier_lds_only();

        // ---- issue next tile's gather; lands under GEMM1+GEMM2 ----
        issue(min(tile + STRIDE, NTILES - 1));

        // ---- GEMM1: C1[h][edge] = wa^T x + ba (this wave: hb, eg1) ----
        {
            float4v C1[2][NT1];
            #pragma unroll
            for (int mt = 0; mt < 2; ++mt)
                #pragma unroll
                for (int nt = 0; nt < NT1; ++nt)
                    #pragma unroll
                    for (int r = 0; r < 4; ++r) C1[mt][nt][r] = bav[mt][r];
            #pragma unroll
            for (int pk = 0; pk < NS1; ++pk)
                #pragma unroll
                for (int nt = 0; nt < NT1; ++nt) {
                    short8 xh = *(const short8*)(xs + (eg1*E1 + nt*16 + c)*RSX + pk*32 + g*8);
                    #pragma unroll
                    for (int mt = 0; mt < 2; ++mt)   // one read feeds 2 MFMAs
                        C1[mt][nt] = __builtin_amdgcn_mfma_f32_16x16x32_bf16(wah[mt][pk], xh, C1[mt][nt], 0,0,0);
                }
            // epilogue1: relu -> packed bf16 -> ys[edge][h]
            #pragma unroll
            for (int mt = 0; mt < 2; ++mt)
                #pragma unroll
                for (int nt = 0; nt < NT1; ++nt) {
                    uint2v pv;
                    pv[0] = cvt_pk_bf16(fmaxf(C1[mt][nt][0], 0.f), fmaxf(C1[mt][nt][1], 0.f));
                    pv[1] = cvt_pk_bf16(fmaxf(C1[mt][nt][2], 0.f), fmaxf(C1[mt][nt][3], 0.f));
                    *(uint2v*)(ys + (eg1*E1 + nt*16 + c)*RSY + hb*32 + mt*16 + g*4) = pv;
                }
        }
        barrier_lds_only();

        // ---- GEMM2 (flipped): C2[edge][o] = y wb + bb (this wave: cb2, eg2) ----
        float4v C2[MT2][2];
        #pragma unroll
        for (int mt = 0; mt < MT2; ++mt)
            #pragma unroll
            for (int cb = 0; cb < 2; ++cb)
                #pragma unroll
                for (int r = 0; r < 4; ++r) C2[mt][cb][r] = bbsc[cb];
        #pragma unroll
        for (int pk = 0; pk < NS2; ++pk)
            #pragma unroll
            for (int mt = 0; mt < MT2; ++mt) {
                short8 yh = *(const short8*)(ys + (eg2*E2 + mt*16 + c)*RSY + pk*32 + g*8);
                #pragma unroll
                for (int cb = 0; cb < 2; ++cb)       // one read feeds 2 MFMAs
                    C2[mt][cb] = __builtin_amdgcn_mfma_f32_16x16x32_bf16(yh, wbh[cb][pk], C2[mt][cb], 0,0,0);
            }
        // epilogue2: rows are edges (edge = g*4+r within the m-tile = node) ->
        // lane-local max over r, then VALU permlane reduce over g; lanes 0..15
        // store 16 consecutive channels.
        #pragma unroll
        for (int mt = 0; mt < MT2; ++mt)
            #pragma unroll
            for (int cb = 0; cb < 2; ++cb) {
                float m = fmaxf(fmaxf(C2[mt][cb][0], C2[mt][cb][1]),
                                fmaxf(C2[mt][cb][2], C2[mt][cb][3]));
                m = red_groups_max(m);
                if (lane < 16) {
                    const int node = tile*4 + eg2*(E2/16) + mt;
                    hout[(size_t)node*O + cb2*32 + cb*16 + lane] = (ushort_t)f2bf(fmaxf(m, 0.f));
                }
            }
        // 2 barriers/tile is safe: a wave reaches stage(t+1) only after epi2(t);
        // barrier-1(t+1) orders xs writes vs all waves' GEMM1(t) reads, and
        // between barriers GEMM2 touches only ys.
    }
}

__global__ void zero_k(float* __restrict__ p, int n)
{
    const int i = blockIdx.x * 256 + threadIdx.x;
    if (i < n) p[i] = 0.f;
}

// batch is SORTED: register accumulation, one atomic per batch-change.
__global__ void pool_k(const ushort_t* __restrict__ h3, const int* __restrict__ batch,
                       float* __restrict__ pooled, float* __restrict__ counts)
{
    const int c    = threadIdx.x & 127;
    const int half = threadIdx.x >> 7;
    const int nbeg = blockIdx.x * 128 + half * 64;
    if (nbeg >= NNODES) return;
    const int nend = min(nbeg + 64, NNODES);

    int   cur = batch[nbeg];
    float acc = 0.f;
    int   runlen = 0;
    for (int n = nbeg; n < nend; ++n) {
        const int b = batch[n];
        if (b != cur) {
            atomicAdd(pooled + cur*128 + c, acc);
            if (c == 0) atomicAdd(counts + cur, (float)runlen);
            acc = 0.f; runlen = 0; cur = b;
        }
        acc += b2f((short)h3[(size_t)n * 128 + c]);
        ++runlen;
    }
    atomicAdd(pooled + cur*128 + c, acc);
    if (c == 0) atomicAdd(counts + cur, (float)runlen);
}

__global__ void reg_k(const float* __restrict__ pooled, const float* __restrict__ counts,
                      const float* __restrict__ wr1, const float* __restrict__ br1,
                      const float* __restrict__ wr2, const float* __restrict__ br2,
                      float* __restrict__ out)
{
    const int b = blockIdx.x;     // 64 blocks
    const int h = threadIdx.x;    // 64 threads = hidden dim
    const float rc = 1.f / fmaxf(counts[b], 1.f);
    float acc = br1[h];
    #pragma unroll
    for (int k = 0; k < 128; ++k)
        acc = fmaf(pooled[b*128 + k] * rc, wr1[k*64 + h], acc);
    float v = acc * wr2[h];
    #pragma unroll
    for (int s = 1; s < 64; s <<= 1)
        v += __shfl_xor(v, s);
    if (h == 0) out[b] = 1.f / (1.f + expf(-(v + br2[0])));
}

extern "C" void kernel_launch(void* const* d_in, const int* in_sizes, int n_in,
                              void* d_out, int out_size, void* d_ws, size_t ws_size,
                              hipStream_t stream)
{
    const float* pos   = (const float*)d_in[0];
    const int*   eidx  = (const int*)d_in[1];    // [2,E]; row 0 = src
    const int*   batch = (const int*)d_in[2];
    // d_in[3] = timestep: unused by the reference
    const float *w1a = (const float*)d_in[4],  *b1a = (const float*)d_in[5];
    const float *w1b = (const float*)d_in[6],  *b1b = (const float*)d_in[7];
    const float *w2a = (const float*)d_in[8],  *b2a = (const float*)d_in[9];
    const float *w2b = (const float*)d_in[10], *b2b = (const float*)d_in[11];
    const float *w3a = (const float*)d_in[12], *b3a = (const float*)d_in[13];
    const float *w3b = (const float*)d_in[14], *b3b = (const float*)d_in[15];
    const float *wr1 = (const float*)d_in[16], *br1 = (const float*)d_in[17];
    const float *wr2 = (const float*)d_in[18], *br2 = (const float*)d_in[19];
    const int* srcArr = eidx;                    // row 0

    // bf16 hidden planes in workspace
    ushort_t* h1 = (ushort_t*)d_ws;                          // N*64 bf16
    ushort_t* h2 = h1 + (size_t)NNODES * 64;                 // N*64 bf16
    ushort_t* h3 = h2 + (size_t)NNODES * 64;                 // N*128 bf16
    float* pooled = (float*)(h3 + (size_t)NNODES * 128);     // B*128 f32
    float* counts = pooled + NBATCH * 128;                   // B
    float* out    = (float*)d_out;

    // L1: 4 waves, MINW=6 (85-reg cap). L2/L3: 8 waves, MINW=4 (128-reg cap,
    // 2 blocks/CU). Grids sized to residency.
    layer_mfma<3,  64, 64, 4, 6><<<1536, dim3(256), 0, stream>>>(nullptr, pos, srcArr, w1a, b1a, w1b, b1b, h1);
    layer_mfma<64, 64, 64, 8, 4><<< 512, dim3(512), 0, stream>>>(h1,      pos, srcArr, w2a, b2a, w2b, b2b, h2);
    layer_mfma<64, 128,128,8, 4><<< 512, dim3(512), 0, stream>>>(h2,      pos, srcArr, w3a, b3a, w3b, b3b, h3);
    zero_k<<<(NBATCH*128 + NBATCH + 255)/256, dim3(256), 0, stream>>>(pooled, NBATCH*128 + NBATCH);
    pool_k<<<(NNODES + 127)/128, dim3(256), 0, stream>>>(h3, batch, pooled, counts);
    reg_k <<<NBATCH, dim3(64), 0, stream>>>(pooled, counts, wr1, br1, wr2, br2, out);
}